// Round 1
// baseline (1154.784 us; speedup 1.0000x reference)
//
#include <hip/hip_runtime.h>

// GCNII layer: N=100000 nodes, C=128, E=640000 edges, fp32.
//   hidden = (1-ALPHA) * segment_sum(attr * x[col], row) + ALPHA * init_x
//   out    = BETA * (hidden @ W) + (1-BETA) * hidden
// hidden lives in d_out (in-place GEMM epilogue; rows partition by wave).

#define ALPHA 0.1f
#define BETA  0.5f
#define C_DIM 128

// K1: hidden = ALPHA * init_x
__global__ void k_init(const float4* __restrict__ init_x,
                       float4* __restrict__ hidden, int n4) {
    int i = blockIdx.x * blockDim.x + threadIdx.x;
    if (i < n4) {
        float4 v = init_x[i];
        v.x *= ALPHA; v.y *= ALPHA; v.z *= ALPHA; v.w *= ALPHA;
        hidden[i] = v;
    }
}

// K2: hidden[row] += (1-ALPHA) * attr[e] * x[col]
// 32 threads per edge, each thread handles 4 contiguous channels (float4).
__global__ void k_scatter(const float* __restrict__ x,
                          const int* __restrict__ ei,     // [2][E] int32
                          const float* __restrict__ attr,
                          float* __restrict__ hidden, int E) {
    int t = blockIdx.x * 256 + threadIdx.x;
    int e  = t >> 5;
    if (e >= E) return;
    int c4 = t & 31;                      // float4 slot: channels c4*4..c4*4+3
    int row = ei[e];
    int col = ei[E + e];
    float a = (1.0f - ALPHA) * attr[e];
    float4 xv = ((const float4*)x)[(size_t)col * (C_DIM / 4) + c4];
    float* h = hidden + (size_t)row * C_DIM + c4 * 4;
    atomicAdd(h + 0, a * xv.x);
    atomicAdd(h + 1, a * xv.y);
    atomicAdd(h + 2, a * xv.z);
    atomicAdd(h + 3, a * xv.w);
}

// K3: in-place  h = BETA*(h @ W) + (1-BETA)*h
// Block: 256 threads = 64 rows; thread (ty,tx) owns rows ty*4..+3, cols tx*8..+7.
// Row ownership partitions by wave (ty = tid>>4, wave = tid>>6), so the
// in-place overwrite is race-free: a wave stores only after its own k-loop
// loads, and no other wave reads its rows (clamped-tail reads are discarded).
__global__ __launch_bounds__(256, 2)
void k_gemm_blend(const float* __restrict__ W, float* __restrict__ h, int N) {
    __shared__ float4 Wl4[C_DIM * C_DIM / 4];   // 64 KB, W row-major [k][c]
    int tid = threadIdx.x;

    const float4* W4 = (const float4*)W;
    for (int i = tid; i < C_DIM * C_DIM / 4; i += 256) Wl4[i] = W4[i];
    __syncthreads();

    int ty = tid >> 4;     // 0..15 -> row group
    int tx = tid & 15;     // 0..15 -> col group (8 cols)
    int r0 = blockIdx.x * 64 + ty * 4;

    float acc[4][8];
#pragma unroll
    for (int i = 0; i < 4; ++i)
#pragma unroll
        for (int j = 0; j < 8; ++j) acc[i][j] = 0.0f;

    const float4* hrow[4];
#pragma unroll
    for (int i = 0; i < 4; ++i) {
        int r = r0 + i; if (r >= N) r = N - 1;   // clamp: results discarded
        hrow[i] = (const float4*)(h + (size_t)r * C_DIM);
    }

    for (int k4 = 0; k4 < C_DIM / 4; ++k4) {
        float4 hv[4];
#pragma unroll
        for (int i = 0; i < 4; ++i) hv[i] = hrow[i][k4];
#pragma unroll
        for (int kk = 0; kk < 4; ++kk) {
            int k = k4 * 4 + kk;
            float4 w0 = Wl4[(k * C_DIM + tx * 8) >> 2];
            float4 w1 = Wl4[(k * C_DIM + tx * 8 + 4) >> 2];
#pragma unroll
            for (int i = 0; i < 4; ++i) {
                float hk = (kk == 0) ? hv[i].x : (kk == 1) ? hv[i].y
                         : (kk == 2) ? hv[i].z : hv[i].w;
                acc[i][0] += hk * w0.x; acc[i][1] += hk * w0.y;
                acc[i][2] += hk * w0.z; acc[i][3] += hk * w0.w;
                acc[i][4] += hk * w1.x; acc[i][5] += hk * w1.y;
                acc[i][6] += hk * w1.z; acc[i][7] += hk * w1.w;
            }
        }
    }

#pragma unroll
    for (int i = 0; i < 4; ++i) {
        int r = r0 + i;
        if (r >= N) continue;
        float* hr = h + (size_t)r * C_DIM + tx * 8;
        float4 h0 = ((const float4*)hr)[0];
        float4 h1 = ((const float4*)hr)[1];
        float4 o0, o1;
        o0.x = BETA * acc[i][0] + (1.0f - BETA) * h0.x;
        o0.y = BETA * acc[i][1] + (1.0f - BETA) * h0.y;
        o0.z = BETA * acc[i][2] + (1.0f - BETA) * h0.z;
        o0.w = BETA * acc[i][3] + (1.0f - BETA) * h0.w;
        o1.x = BETA * acc[i][4] + (1.0f - BETA) * h1.x;
        o1.y = BETA * acc[i][5] + (1.0f - BETA) * h1.y;
        o1.z = BETA * acc[i][6] + (1.0f - BETA) * h1.z;
        o1.w = BETA * acc[i][7] + (1.0f - BETA) * h1.w;
        ((float4*)hr)[0] = o0;
        ((float4*)hr)[1] = o1;
    }
}

extern "C" void kernel_launch(void* const* d_in, const int* in_sizes, int n_in,
                              void* d_out, int out_size, void* d_ws, size_t ws_size,
                              hipStream_t stream) {
    const float* x      = (const float*)d_in[0];
    const int*   ei     = (const int*)d_in[1];
    const float* attr   = (const float*)d_in[2];
    const float* init_x = (const float*)d_in[3];
    const float* W      = (const float*)d_in[4];
    float* out = (float*)d_out;

    const int N = in_sizes[0] / C_DIM;
    const int E = in_sizes[2];
    const int n4 = N * C_DIM / 4;

    k_init<<<(n4 + 255) / 256, 256, 0, stream>>>((const float4*)init_x,
                                                 (float4*)out, n4);

    int scatter_blocks = (E * 32 + 255) / 256;
    k_scatter<<<scatter_blocks, 256, 0, stream>>>(x, ei, attr, out, E);

    k_gemm_blend<<<(N + 63) / 64, 256, 0, stream>>>(W, out, N);
}

// Round 2
// 205.172 us; speedup vs baseline: 5.6284x; 5.6284x over previous
//
#include <hip/hip_runtime.h>

// GCNII layer: N=100000 nodes, C=128, E=640000 edges, fp32.
//   hidden = (1-ALPHA) * segment_sum(attr * x[col], row) + ALPHA * init_x
//   out    = BETA * (hidden @ W) + (1-BETA) * hidden
//
// Strategy: build CSR per call (counting sort by row: hist -> scan -> bin),
// then gather-reduce per row (no float atomics), then in-place GEMM blend.
// Workspace: cnt[N] ints | partials[256] ints | cols_s[E] ints | attr_s[E] floats.

#define ALPHA 0.1f
#define BETA  0.5f
#define C_DIM 128

__global__ void k_zero(int* __restrict__ p, int n) {
    int i = blockIdx.x * 256 + threadIdx.x;
    if (i < n) p[i] = 0;
}

__global__ void k_hist(const int* __restrict__ ei, int* __restrict__ cnt, int E) {
    int e = blockIdx.x * 256 + threadIdx.x;
    if (e < E) atomicAdd(&cnt[ei[e]], 1);
}

// partials[b] = sum of cnt[b*1024 .. b*1024+1024)
__global__ void k_blockreduce(const int* __restrict__ cnt, int* __restrict__ partials, int n) {
    __shared__ int lds[256];
    int t = threadIdx.x;
    int base = blockIdx.x * 1024;
    int s = 0;
#pragma unroll
    for (int j = 0; j < 4; ++j) {
        int idx = base + j * 256 + t;
        if (idx < n) s += cnt[idx];
    }
    lds[t] = s;
    __syncthreads();
    for (int d = 128; d > 0; d >>= 1) {
        if (t < d) lds[t] += lds[t + d];
        __syncthreads();
    }
    if (t == 0) partials[blockIdx.x] = lds[0];
}

// single block: in-place EXCLUSIVE scan of partials[0..B), B<=256
__global__ void k_scan_partials(int* __restrict__ partials, int B) {
    __shared__ int lds[256];
    int t = threadIdx.x;
    int v = (t < B) ? partials[t] : 0;
    lds[t] = v;
    for (int d = 1; d < 256; d <<= 1) {
        __syncthreads();
        int tmp = (t >= d) ? lds[t - d] : 0;
        __syncthreads();
        lds[t] += tmp;
    }
    __syncthreads();
    if (t < B) partials[t] = lds[t] - v;
}

// block b: exclusive scan of cnt[b*1024 ..], in place, plus partials[b]
__global__ void k_blockscan(int* __restrict__ cnt, const int* __restrict__ partials, int n) {
    __shared__ int lds[256];
    int t = threadIdx.x;
    int base = blockIdx.x * 1024 + t * 4;
    int4 v = {0, 0, 0, 0};
    if (base + 3 < n) v = *(const int4*)(cnt + base);
    else {
        if (base + 0 < n) v.x = cnt[base + 0];
        if (base + 1 < n) v.y = cnt[base + 1];
        if (base + 2 < n) v.z = cnt[base + 2];
        if (base + 3 < n) v.w = cnt[base + 3];
    }
    int s = v.x + v.y + v.z + v.w;
    lds[t] = s;
    for (int d = 1; d < 256; d <<= 1) {
        __syncthreads();
        int tmp = (t >= d) ? lds[t - d] : 0;
        __syncthreads();
        lds[t] += tmp;
    }
    __syncthreads();
    int thrBase = partials[blockIdx.x] + lds[t] - s;   // exclusive base for elem 0
    int4 o;
    o.x = thrBase;
    o.y = thrBase + v.x;
    o.z = thrBase + v.x + v.y;
    o.w = thrBase + v.x + v.y + v.z;
    if (base + 3 < n) *(int4*)(cnt + base) = o;
    else {
        if (base + 0 < n) cnt[base + 0] = o.x;
        if (base + 1 < n) cnt[base + 1] = o.y;
        if (base + 2 < n) cnt[base + 2] = o.z;
        if (base + 3 < n) cnt[base + 3] = o.w;
    }
}

// bin edges into CSR order; cnt acts as cursor (post: cnt[r] = row_end[r])
__global__ void k_build(const int* __restrict__ ei, const float* __restrict__ attr,
                        int* __restrict__ cur, int* __restrict__ cols_s,
                        float* __restrict__ attr_s, int E) {
    int e = blockIdx.x * 256 + threadIdx.x;
    if (e >= E) return;
    int row = ei[e];
    int pos = atomicAdd(&cur[row], 1);
    cols_s[pos] = ei[E + e];
    attr_s[pos] = (1.0f - ALPHA) * attr[e];
}

// per-row gather-reduce + ALPHA*init_x epilogue. 32 threads/row (float4 lanes).
// post-build cnt[r] = end of row r; start = cnt[r-1] (0 for r==0).
__global__ __launch_bounds__(256)
void k_gather(const float4* __restrict__ x4, const int* __restrict__ cnt,
              const int* __restrict__ cols_s, const float* __restrict__ attr_s,
              const float4* __restrict__ init4, float4* __restrict__ out4, int N) {
    int r = blockIdx.x * 8 + (threadIdx.x >> 5);
    if (r >= N) return;
    int c4 = threadIdx.x & 31;
    int start = (r == 0) ? 0 : cnt[r - 1];
    int end = cnt[r];
    float4 acc = {0.f, 0.f, 0.f, 0.f};
    for (int k = start; k < end; ++k) {
        int col = cols_s[k];
        float a = attr_s[k];
        float4 xv = x4[(size_t)col * 32 + c4];
        acc.x += a * xv.x; acc.y += a * xv.y;
        acc.z += a * xv.z; acc.w += a * xv.w;
    }
    float4 iv = init4[(size_t)r * 32 + c4];
    float4 o;
    o.x = acc.x + ALPHA * iv.x;
    o.y = acc.y + ALPHA * iv.y;
    o.z = acc.z + ALPHA * iv.z;
    o.w = acc.w + ALPHA * iv.w;
    out4[(size_t)r * 32 + c4] = o;
}

// in-place  h = BETA*(h @ W) + (1-BETA)*h   (rows partition by wave; race-free)
__global__ __launch_bounds__(256, 2)
void k_gemm_blend(const float* __restrict__ W, float* __restrict__ h, int N) {
    __shared__ float4 Wl4[C_DIM * C_DIM / 4];   // 64 KB, W row-major [k][c]
    int tid = threadIdx.x;

    const float4* W4 = (const float4*)W;
    for (int i = tid; i < C_DIM * C_DIM / 4; i += 256) Wl4[i] = W4[i];
    __syncthreads();

    int ty = tid >> 4;
    int tx = tid & 15;
    int r0 = blockIdx.x * 64 + ty * 4;

    float acc[4][8];
#pragma unroll
    for (int i = 0; i < 4; ++i)
#pragma unroll
        for (int j = 0; j < 8; ++j) acc[i][j] = 0.0f;

    const float4* hrow[4];
#pragma unroll
    for (int i = 0; i < 4; ++i) {
        int r = r0 + i; if (r >= N) r = N - 1;   // clamp: results discarded
        hrow[i] = (const float4*)(h + (size_t)r * C_DIM);
    }

    for (int k4 = 0; k4 < C_DIM / 4; ++k4) {
        float4 hv[4];
#pragma unroll
        for (int i = 0; i < 4; ++i) hv[i] = hrow[i][k4];
#pragma unroll
        for (int kk = 0; kk < 4; ++kk) {
            int k = k4 * 4 + kk;
            float4 w0 = Wl4[(k * C_DIM + tx * 8) >> 2];
            float4 w1 = Wl4[(k * C_DIM + tx * 8 + 4) >> 2];
#pragma unroll
            for (int i = 0; i < 4; ++i) {
                float hk = (kk == 0) ? hv[i].x : (kk == 1) ? hv[i].y
                         : (kk == 2) ? hv[i].z : hv[i].w;
                acc[i][0] += hk * w0.x; acc[i][1] += hk * w0.y;
                acc[i][2] += hk * w0.z; acc[i][3] += hk * w0.w;
                acc[i][4] += hk * w1.x; acc[i][5] += hk * w1.y;
                acc[i][6] += hk * w1.z; acc[i][7] += hk * w1.w;
            }
        }
    }

#pragma unroll
    for (int i = 0; i < 4; ++i) {
        int r = r0 + i;
        if (r >= N) continue;
        float* hr = h + (size_t)r * C_DIM + tx * 8;
        float4 h0 = ((const float4*)hr)[0];
        float4 h1 = ((const float4*)hr)[1];
        float4 o0, o1;
        o0.x = BETA * acc[i][0] + (1.0f - BETA) * h0.x;
        o0.y = BETA * acc[i][1] + (1.0f - BETA) * h0.y;
        o0.z = BETA * acc[i][2] + (1.0f - BETA) * h0.z;
        o0.w = BETA * acc[i][3] + (1.0f - BETA) * h0.w;
        o1.x = BETA * acc[i][4] + (1.0f - BETA) * h1.x;
        o1.y = BETA * acc[i][5] + (1.0f - BETA) * h1.y;
        o1.z = BETA * acc[i][6] + (1.0f - BETA) * h1.z;
        o1.w = BETA * acc[i][7] + (1.0f - BETA) * h1.w;
        ((float4*)hr)[0] = o0;
        ((float4*)hr)[1] = o1;
    }
}

extern "C" void kernel_launch(void* const* d_in, const int* in_sizes, int n_in,
                              void* d_out, int out_size, void* d_ws, size_t ws_size,
                              hipStream_t stream) {
    const float* x      = (const float*)d_in[0];
    const int*   ei     = (const int*)d_in[1];
    const float* attr   = (const float*)d_in[2];
    const float* init_x = (const float*)d_in[3];
    const float* W      = (const float*)d_in[4];
    float* out = (float*)d_out;

    const int N = in_sizes[0] / C_DIM;
    const int E = in_sizes[2];

    // workspace layout
    int N_pad = (N + 255) & ~255;
    int*   cnt      = (int*)d_ws;          // N ints (cursor/offsets)
    int*   partials = cnt + N_pad;         // 256 ints
    int*   cols_s   = partials + 256;      // E ints
    float* attr_s   = (float*)(cols_s + E);// E floats

    const int B = (N + 1023) / 1024;       // scan blocks (98 for N=100000)

    k_zero<<<(N + 255) / 256, 256, 0, stream>>>(cnt, N);
    k_hist<<<(E + 255) / 256, 256, 0, stream>>>(ei, cnt, E);
    k_blockreduce<<<B, 256, 0, stream>>>(cnt, partials, N);
    k_scan_partials<<<1, 256, 0, stream>>>(partials, B);
    k_blockscan<<<B, 256, 0, stream>>>(cnt, partials, N);
    k_build<<<(E + 255) / 256, 256, 0, stream>>>(ei, attr, cnt, cols_s, attr_s, E);
    k_gather<<<(N + 7) / 8, 256, 0, stream>>>((const float4*)x, cnt, cols_s, attr_s,
                                              (const float4*)init_x, (float4*)out, N);
    k_gemm_blend<<<(N + 63) / 64, 256, 0, stream>>>(W, out, N);
}

// Round 3
// 195.681 us; speedup vs baseline: 5.9014x; 1.0485x over previous
//
#include <hip/hip_runtime.h>

// GCNII layer: N=100000 nodes, C=128, E=640000 edges, fp32.
//   hidden = (1-ALPHA) * segment_sum(attr * x[col], row) + ALPHA * init_x
//   out    = BETA * (hidden @ W) + (1-BETA) * hidden
//
// Pipeline: prep (x->bf16 copy + zero cnt) -> hist -> blockreduce ->
// blockscan (self-computed base) -> build packed CSR records ->
// gather-reduce (bf16 x rows, fp32 acc) -> in-place GEMM blend.
// Workspace: xb[N*128 bf16] | cnt[N] | partials[256] | recs[E float2].

#define ALPHA 0.1f
#define BETA  0.5f
#define C_DIM 128

__device__ inline unsigned bf16rn(float f) {            // RTNE fp32->bf16 bits
    unsigned u = __float_as_uint(f);
    return (u + 0x7FFFu + ((u >> 16) & 1u)) >> 16;
}
__device__ inline unsigned pack2(float lo, float hi) {
    return bf16rn(lo) | (bf16rn(hi) << 16);
}

// K0: convert x -> bf16 (8 elems/thread) and zero cnt[N]. xb may be null.
__global__ void k_prep(const float4* __restrict__ x4, uint4* __restrict__ xb,
                       int n8, int* __restrict__ cnt, int N) {
    int i = blockIdx.x * 256 + threadIdx.x;
    if (i < n8) {
        float4 a = x4[2 * i], b = x4[2 * i + 1];
        uint4 o;
        o.x = pack2(a.x, a.y); o.y = pack2(a.z, a.w);
        o.z = pack2(b.x, b.y); o.w = pack2(b.z, b.w);
        xb[i] = o;
    }
    if (i < N) cnt[i] = 0;
}

__global__ void k_hist(const int* __restrict__ ei, int* __restrict__ cnt, int E) {
    int e = blockIdx.x * 256 + threadIdx.x;
    if (e < E) atomicAdd(&cnt[ei[e]], 1);
}

// partials[b] = sum of cnt[b*1024 .. b*1024+1024)
__global__ void k_blockreduce(const int* __restrict__ cnt, int* __restrict__ partials, int n) {
    __shared__ int lds[256];
    int t = threadIdx.x;
    int base = blockIdx.x * 1024;
    int s = 0;
#pragma unroll
    for (int j = 0; j < 4; ++j) {
        int idx = base + j * 256 + t;
        if (idx < n) s += cnt[idx];
    }
    lds[t] = s;
    __syncthreads();
    for (int d = 128; d > 0; d >>= 1) {
        if (t < d) lds[t] += lds[t + d];
        __syncthreads();
    }
    if (t == 0) partials[blockIdx.x] = lds[0];
}

// block b: exclusive scan of cnt[b*1024 ..] in place; base = sum(partials[<b])
// (requires gridDim.x <= 256)
__global__ void k_blockscan(int* __restrict__ cnt, const int* __restrict__ partials, int n) {
    __shared__ int lds[256];
    __shared__ int base_s;
    int t = threadIdx.x;

    // 1) base = sum of partials[t < blockIdx.x]
    int pv = (t < blockIdx.x) ? partials[t] : 0;
    lds[t] = pv;
    __syncthreads();
    for (int d = 128; d > 0; d >>= 1) {
        if (t < d) lds[t] += lds[t + d];
        __syncthreads();
    }
    if (t == 0) base_s = lds[0];
    __syncthreads();

    // 2) scan own 1024 (int4 per thread)
    int base = blockIdx.x * 1024 + t * 4;
    int4 v = {0, 0, 0, 0};
    if (base + 3 < n) v = *(const int4*)(cnt + base);
    else {
        if (base + 0 < n) v.x = cnt[base + 0];
        if (base + 1 < n) v.y = cnt[base + 1];
        if (base + 2 < n) v.z = cnt[base + 2];
        if (base + 3 < n) v.w = cnt[base + 3];
    }
    int s = v.x + v.y + v.z + v.w;
    lds[t] = s;
    for (int d = 1; d < 256; d <<= 1) {
        __syncthreads();
        int tmp = (t >= d) ? lds[t - d] : 0;
        __syncthreads();
        lds[t] += tmp;
    }
    __syncthreads();
    int thrBase = base_s + lds[t] - s;
    int4 o;
    o.x = thrBase;
    o.y = thrBase + v.x;
    o.z = thrBase + v.x + v.y;
    o.w = thrBase + v.x + v.y + v.z;
    if (base + 3 < n) *(int4*)(cnt + base) = o;
    else {
        if (base + 0 < n) cnt[base + 0] = o.x;
        if (base + 1 < n) cnt[base + 1] = o.y;
        if (base + 2 < n) cnt[base + 2] = o.z;
        if (base + 3 < n) cnt[base + 3] = o.w;
    }
}

// bin edges into CSR order as packed 8B records (col, attr*(1-ALPHA))
__global__ void k_build(const int* __restrict__ ei, const float* __restrict__ attr,
                        int* __restrict__ cur, float2* __restrict__ recs, int E) {
    int e = blockIdx.x * 256 + threadIdx.x;
    if (e >= E) return;
    int row = ei[e];
    int pos = atomicAdd(&cur[row], 1);
    recs[pos] = make_float2(__int_as_float(ei[E + e]), (1.0f - ALPHA) * attr[e]);
}

// per-row gather-reduce + ALPHA*init_x. 32 lanes/row, 4 channels/lane.
// post-build cnt[r] = end of row r; start = cnt[r-1].
template <int USE_BF16>
__global__ __launch_bounds__(256)
void k_gather(const void* __restrict__ xsrc, const int* __restrict__ cnt,
              const float2* __restrict__ recs,
              const float4* __restrict__ init4, float4* __restrict__ out4, int N) {
    int r = blockIdx.x * 8 + (threadIdx.x >> 5);
    if (r >= N) return;
    int c4 = threadIdx.x & 31;
    int start = (r == 0) ? 0 : cnt[r - 1];
    int end = cnt[r];
    float4 acc = {0.f, 0.f, 0.f, 0.f};
    if (USE_BF16) {
        const uint2* xb2 = (const uint2*)xsrc;
        for (int k = start; k < end; ++k) {
            float2 rec = recs[k];
            int col = __float_as_int(rec.x);
            float a = rec.y;
            uint2 v = xb2[(size_t)col * 32 + c4];
            acc.x += a * __uint_as_float(v.x << 16);
            acc.y += a * __uint_as_float(v.x & 0xffff0000u);
            acc.z += a * __uint_as_float(v.y << 16);
            acc.w += a * __uint_as_float(v.y & 0xffff0000u);
        }
    } else {
        const float4* x4 = (const float4*)xsrc;
        for (int k = start; k < end; ++k) {
            float2 rec = recs[k];
            int col = __float_as_int(rec.x);
            float a = rec.y;
            float4 xv = x4[(size_t)col * 32 + c4];
            acc.x += a * xv.x; acc.y += a * xv.y;
            acc.z += a * xv.z; acc.w += a * xv.w;
        }
    }
    float4 iv = init4[(size_t)r * 32 + c4];
    float4 o;
    o.x = acc.x + ALPHA * iv.x;
    o.y = acc.y + ALPHA * iv.y;
    o.z = acc.z + ALPHA * iv.z;
    o.w = acc.w + ALPHA * iv.w;
    out4[(size_t)r * 32 + c4] = o;
}

// in-place  h = BETA*(h @ W) + (1-BETA)*h   (rows partition by wave; race-free)
__global__ __launch_bounds__(256, 2)
void k_gemm_blend(const float* __restrict__ W, float* __restrict__ h, int N) {
    __shared__ float4 Wl4[C_DIM * C_DIM / 4];   // 64 KB, W row-major [k][c]
    int tid = threadIdx.x;

    const float4* W4 = (const float4*)W;
    for (int i = tid; i < C_DIM * C_DIM / 4; i += 256) Wl4[i] = W4[i];
    __syncthreads();

    int ty = tid >> 4;
    int tx = tid & 15;
    int r0 = blockIdx.x * 64 + ty * 4;

    float acc[4][8];
#pragma unroll
    for (int i = 0; i < 4; ++i)
#pragma unroll
        for (int j = 0; j < 8; ++j) acc[i][j] = 0.0f;

    const float4* hrow[4];
#pragma unroll
    for (int i = 0; i < 4; ++i) {
        int r = r0 + i; if (r >= N) r = N - 1;   // clamp: results discarded
        hrow[i] = (const float4*)(h + (size_t)r * C_DIM);
    }

    for (int k4 = 0; k4 < C_DIM / 4; ++k4) {
        float4 hv[4];
#pragma unroll
        for (int i = 0; i < 4; ++i) hv[i] = hrow[i][k4];
#pragma unroll
        for (int kk = 0; kk < 4; ++kk) {
            int k = k4 * 4 + kk;
            float4 w0 = Wl4[(k * C_DIM + tx * 8) >> 2];
            float4 w1 = Wl4[(k * C_DIM + tx * 8 + 4) >> 2];
#pragma unroll
            for (int i = 0; i < 4; ++i) {
                float hk = (kk == 0) ? hv[i].x : (kk == 1) ? hv[i].y
                         : (kk == 2) ? hv[i].z : hv[i].w;
                acc[i][0] += hk * w0.x; acc[i][1] += hk * w0.y;
                acc[i][2] += hk * w0.z; acc[i][3] += hk * w0.w;
                acc[i][4] += hk * w1.x; acc[i][5] += hk * w1.y;
                acc[i][6] += hk * w1.z; acc[i][7] += hk * w1.w;
            }
        }
    }

#pragma unroll
    for (int i = 0; i < 4; ++i) {
        int r = r0 + i;
        if (r >= N) continue;
        float* hr = h + (size_t)r * C_DIM + tx * 8;
        float4 h0 = ((const float4*)hr)[0];
        float4 h1 = ((const float4*)hr)[1];
        float4 o0, o1;
        o0.x = BETA * acc[i][0] + (1.0f - BETA) * h0.x;
        o0.y = BETA * acc[i][1] + (1.0f - BETA) * h0.y;
        o0.z = BETA * acc[i][2] + (1.0f - BETA) * h0.z;
        o0.w = BETA * acc[i][3] + (1.0f - BETA) * h0.w;
        o1.x = BETA * acc[i][4] + (1.0f - BETA) * h1.x;
        o1.y = BETA * acc[i][5] + (1.0f - BETA) * h1.y;
        o1.z = BETA * acc[i][6] + (1.0f - BETA) * h1.z;
        o1.w = BETA * acc[i][7] + (1.0f - BETA) * h1.w;
        ((float4*)hr)[0] = o0;
        ((float4*)hr)[1] = o1;
    }
}

extern "C" void kernel_launch(void* const* d_in, const int* in_sizes, int n_in,
                              void* d_out, int out_size, void* d_ws, size_t ws_size,
                              hipStream_t stream) {
    const float* x      = (const float*)d_in[0];
    const int*   ei     = (const int*)d_in[1];
    const float* attr   = (const float*)d_in[2];
    const float* init_x = (const float*)d_in[3];
    const float* W      = (const float*)d_in[4];
    float* out = (float*)d_out;

    const int N = in_sizes[0] / C_DIM;
    const int E = in_sizes[2];

    const int N_pad = (N + 255) & ~255;
    const size_t xb_bytes  = (size_t)N * C_DIM * 2;       // bf16 copy of x
    const size_t cnt_bytes = (size_t)N_pad * 4;
    const size_t rec_bytes = (size_t)E * 8;
    const size_t need_full = xb_bytes + cnt_bytes + 1024 + rec_bytes;
    const bool use_bf16 = ws_size >= need_full;

    char* wsp = (char*)d_ws;
    uint4* xb = nullptr;
    if (use_bf16) { xb = (uint4*)wsp; wsp += xb_bytes; }
    int*    cnt      = (int*)wsp;
    int*    partials = cnt + N_pad;
    float2* recs     = (float2*)((char*)partials + 1024);

    const int B = (N + 1023) / 1024;   // scan blocks (98 for N=100000), must be <=256
    const int n8 = use_bf16 ? (N * C_DIM / 8) : 0;
    const int prep_elems = (n8 > N) ? n8 : N;

    k_prep<<<(prep_elems + 255) / 256, 256, 0, stream>>>((const float4*)x, xb, n8, cnt, N);
    k_hist<<<(E + 255) / 256, 256, 0, stream>>>(ei, cnt, E);
    k_blockreduce<<<B, 256, 0, stream>>>(cnt, partials, N);
    k_blockscan<<<B, 256, 0, stream>>>(cnt, partials, N);
    k_build<<<(E + 255) / 256, 256, 0, stream>>>(ei, attr, cnt, recs, E);
    if (use_bf16) {
        k_gather<1><<<(N + 7) / 8, 256, 0, stream>>>((const void*)xb, cnt, recs,
                                                     (const float4*)init_x, (float4*)out, N);
    } else {
        k_gather<0><<<(N + 7) / 8, 256, 0, stream>>>((const void*)x, cnt, recs,
                                                     (const float4*)init_x, (float4*)out, N);
    }
    k_gemm_blend<<<(N + 63) / 64, 256, 0, stream>>>(W, out, N);
}

// Round 4
// 182.936 us; speedup vs baseline: 6.3125x; 1.0697x over previous
//
#include <hip/hip_runtime.h>

// GCNII layer: N=100000 nodes, C=128, E=640000 edges, fp32.
//   hidden = (1-ALPHA) * segment_sum(attr * x[col], row) + ALPHA * init_x
//   out    = BETA * (hidden @ W) + (1-BETA) * hidden
//
// Pipeline: prep (x->bf16 copy + zero cnt) -> hist -> blockreduce ->
// blockscan (self-computed base) -> build packed CSR records ->
// gather-reduce (4-way unrolled, bf16 x rows, fp32 acc) -> in-place GEMM blend.
// Workspace: xb[N*128 bf16] | cnt[N] | partials[256] | recs[E float2].

#define ALPHA 0.1f
#define BETA  0.5f
#define C_DIM 128

__device__ inline unsigned bf16rn(float f) {            // RTNE fp32->bf16 bits
    unsigned u = __float_as_uint(f);
    return (u + 0x7FFFu + ((u >> 16) & 1u)) >> 16;
}
__device__ inline unsigned pack2(float lo, float hi) {
    return bf16rn(lo) | (bf16rn(hi) << 16);
}

// K0: convert x -> bf16 (8 elems/thread) and zero cnt[N]. xb may be null.
__global__ void k_prep(const float4* __restrict__ x4, uint4* __restrict__ xb,
                       int n8, int* __restrict__ cnt, int N) {
    int i = blockIdx.x * 256 + threadIdx.x;
    if (i < n8) {
        float4 a = x4[2 * i], b = x4[2 * i + 1];
        uint4 o;
        o.x = pack2(a.x, a.y); o.y = pack2(a.z, a.w);
        o.z = pack2(b.x, b.y); o.w = pack2(b.z, b.w);
        xb[i] = o;
    }
    if (i < N) cnt[i] = 0;
}

__global__ void k_hist(const int* __restrict__ ei, int* __restrict__ cnt, int E) {
    int e = blockIdx.x * 256 + threadIdx.x;
    if (e < E) atomicAdd(&cnt[ei[e]], 1);
}

// partials[b] = sum of cnt[b*1024 .. b*1024+1024)
__global__ void k_blockreduce(const int* __restrict__ cnt, int* __restrict__ partials, int n) {
    __shared__ int lds[256];
    int t = threadIdx.x;
    int base = blockIdx.x * 1024;
    int s = 0;
#pragma unroll
    for (int j = 0; j < 4; ++j) {
        int idx = base + j * 256 + t;
        if (idx < n) s += cnt[idx];
    }
    lds[t] = s;
    __syncthreads();
    for (int d = 128; d > 0; d >>= 1) {
        if (t < d) lds[t] += lds[t + d];
        __syncthreads();
    }
    if (t == 0) partials[blockIdx.x] = lds[0];
}

// block b: exclusive scan of cnt[b*1024 ..] in place; base = sum(partials[<b])
// (requires gridDim.x <= 256)
__global__ void k_blockscan(int* __restrict__ cnt, const int* __restrict__ partials, int n) {
    __shared__ int lds[256];
    __shared__ int base_s;
    int t = threadIdx.x;

    int pv = (t < blockIdx.x) ? partials[t] : 0;
    lds[t] = pv;
    __syncthreads();
    for (int d = 128; d > 0; d >>= 1) {
        if (t < d) lds[t] += lds[t + d];
        __syncthreads();
    }
    if (t == 0) base_s = lds[0];
    __syncthreads();

    int base = blockIdx.x * 1024 + t * 4;
    int4 v = {0, 0, 0, 0};
    if (base + 3 < n) v = *(const int4*)(cnt + base);
    else {
        if (base + 0 < n) v.x = cnt[base + 0];
        if (base + 1 < n) v.y = cnt[base + 1];
        if (base + 2 < n) v.z = cnt[base + 2];
        if (base + 3 < n) v.w = cnt[base + 3];
    }
    int s = v.x + v.y + v.z + v.w;
    lds[t] = s;
    for (int d = 1; d < 256; d <<= 1) {
        __syncthreads();
        int tmp = (t >= d) ? lds[t - d] : 0;
        __syncthreads();
        lds[t] += tmp;
    }
    __syncthreads();
    int thrBase = base_s + lds[t] - s;
    int4 o;
    o.x = thrBase;
    o.y = thrBase + v.x;
    o.z = thrBase + v.x + v.y;
    o.w = thrBase + v.x + v.y + v.z;
    if (base + 3 < n) *(int4*)(cnt + base) = o;
    else {
        if (base + 0 < n) cnt[base + 0] = o.x;
        if (base + 1 < n) cnt[base + 1] = o.y;
        if (base + 2 < n) cnt[base + 2] = o.z;
        if (base + 3 < n) cnt[base + 3] = o.w;
    }
}

// bin edges into CSR order as packed 8B records (col, attr*(1-ALPHA))
__global__ void k_build(const int* __restrict__ ei, const float* __restrict__ attr,
                        int* __restrict__ cur, float2* __restrict__ recs, int E) {
    int e = blockIdx.x * 256 + threadIdx.x;
    if (e >= E) return;
    int row = ei[e];
    int pos = atomicAdd(&cur[row], 1);
    recs[pos] = make_float2(__int_as_float(ei[E + e]), (1.0f - ALPHA) * attr[e]);
}

__device__ inline void bf16_fma4(float4& acc, float a, uint2 v) {
    acc.x += a * __uint_as_float(v.x << 16);
    acc.y += a * __uint_as_float(v.x & 0xffff0000u);
    acc.z += a * __uint_as_float(v.y << 16);
    acc.w += a * __uint_as_float(v.y & 0xffff0000u);
}

// per-row gather-reduce + ALPHA*init_x. 32 lanes/row, 4 channels/lane.
// 4-way edge unroll for memory-level parallelism (edges are latency-bound).
// post-build cnt[r] = end of row r; start = cnt[r-1].
template <int USE_BF16>
__global__ __launch_bounds__(256)
void k_gather(const void* __restrict__ xsrc, const int* __restrict__ cnt,
              const float2* __restrict__ recs,
              const float4* __restrict__ init4, float4* __restrict__ out4, int N) {
    int r = blockIdx.x * 8 + (threadIdx.x >> 5);
    if (r >= N) return;
    int c4 = threadIdx.x & 31;
    int start = (r == 0) ? 0 : cnt[r - 1];
    int end = cnt[r];
    float4 acc = {0.f, 0.f, 0.f, 0.f};
    int k = start;
    if (USE_BF16) {
        const uint2* xb2 = (const uint2*)xsrc;
        for (; k + 4 <= end; k += 4) {
            float2 r0 = recs[k + 0];
            float2 r1 = recs[k + 1];
            float2 r2 = recs[k + 2];
            float2 r3 = recs[k + 3];
            uint2 v0 = xb2[(size_t)__float_as_int(r0.x) * 32 + c4];
            uint2 v1 = xb2[(size_t)__float_as_int(r1.x) * 32 + c4];
            uint2 v2 = xb2[(size_t)__float_as_int(r2.x) * 32 + c4];
            uint2 v3 = xb2[(size_t)__float_as_int(r3.x) * 32 + c4];
            bf16_fma4(acc, r0.y, v0);
            bf16_fma4(acc, r1.y, v1);
            bf16_fma4(acc, r2.y, v2);
            bf16_fma4(acc, r3.y, v3);
        }
        if (k + 2 <= end) {
            float2 r0 = recs[k + 0];
            float2 r1 = recs[k + 1];
            uint2 v0 = xb2[(size_t)__float_as_int(r0.x) * 32 + c4];
            uint2 v1 = xb2[(size_t)__float_as_int(r1.x) * 32 + c4];
            bf16_fma4(acc, r0.y, v0);
            bf16_fma4(acc, r1.y, v1);
            k += 2;
        }
        if (k < end) {
            float2 r0 = recs[k];
            uint2 v0 = xb2[(size_t)__float_as_int(r0.x) * 32 + c4];
            bf16_fma4(acc, r0.y, v0);
        }
    } else {
        const float4* x4 = (const float4*)xsrc;
        for (; k < end; ++k) {
            float2 rec = recs[k];
            int col = __float_as_int(rec.x);
            float a = rec.y;
            float4 xv = x4[(size_t)col * 32 + c4];
            acc.x += a * xv.x; acc.y += a * xv.y;
            acc.z += a * xv.z; acc.w += a * xv.w;
        }
    }
    float4 iv = init4[(size_t)r * 32 + c4];
    float4 o;
    o.x = acc.x + ALPHA * iv.x;
    o.y = acc.y + ALPHA * iv.y;
    o.z = acc.z + ALPHA * iv.z;
    o.w = acc.w + ALPHA * iv.w;
    out4[(size_t)r * 32 + c4] = o;
}

// in-place  h = BETA*(h @ W) + (1-BETA)*h   (rows partition by wave; race-free)
__global__ __launch_bounds__(256, 2)
void k_gemm_blend(const float* __restrict__ W, float* __restrict__ h, int N) {
    __shared__ float4 Wl4[C_DIM * C_DIM / 4];   // 64 KB, W row-major [k][c]
    int tid = threadIdx.x;

    const float4* W4 = (const float4*)W;
    for (int i = tid; i < C_DIM * C_DIM / 4; i += 256) Wl4[i] = W4[i];
    __syncthreads();

    int ty = tid >> 4;
    int tx = tid & 15;
    int r0 = blockIdx.x * 64 + ty * 4;

    float acc[4][8];
#pragma unroll
    for (int i = 0; i < 4; ++i)
#pragma unroll
        for (int j = 0; j < 8; ++j) acc[i][j] = 0.0f;

    const float4* hrow[4];
#pragma unroll
    for (int i = 0; i < 4; ++i) {
        int r = r0 + i; if (r >= N) r = N - 1;   // clamp: results discarded
        hrow[i] = (const float4*)(h + (size_t)r * C_DIM);
    }

    for (int k4 = 0; k4 < C_DIM / 4; ++k4) {
        float4 hv[4];
#pragma unroll
        for (int i = 0; i < 4; ++i) hv[i] = hrow[i][k4];
#pragma unroll
        for (int kk = 0; kk < 4; ++kk) {
            int k = k4 * 4 + kk;
            float4 w0 = Wl4[(k * C_DIM + tx * 8) >> 2];
            float4 w1 = Wl4[(k * C_DIM + tx * 8 + 4) >> 2];
#pragma unroll
            for (int i = 0; i < 4; ++i) {
                float hk = (kk == 0) ? hv[i].x : (kk == 1) ? hv[i].y
                         : (kk == 2) ? hv[i].z : hv[i].w;
                acc[i][0] += hk * w0.x; acc[i][1] += hk * w0.y;
                acc[i][2] += hk * w0.z; acc[i][3] += hk * w0.w;
                acc[i][4] += hk * w1.x; acc[i][5] += hk * w1.y;
                acc[i][6] += hk * w1.z; acc[i][7] += hk * w1.w;
            }
        }
    }

#pragma unroll
    for (int i = 0; i < 4; ++i) {
        int r = r0 + i;
        if (r >= N) continue;
        float* hr = h + (size_t)r * C_DIM + tx * 8;
        float4 h0 = ((const float4*)hr)[0];
        float4 h1 = ((const float4*)hr)[1];
        float4 o0, o1;
        o0.x = BETA * acc[i][0] + (1.0f - BETA) * h0.x;
        o0.y = BETA * acc[i][1] + (1.0f - BETA) * h0.y;
        o0.z = BETA * acc[i][2] + (1.0f - BETA) * h0.z;
        o0.w = BETA * acc[i][3] + (1.0f - BETA) * h0.w;
        o1.x = BETA * acc[i][4] + (1.0f - BETA) * h1.x;
        o1.y = BETA * acc[i][5] + (1.0f - BETA) * h1.y;
        o1.z = BETA * acc[i][6] + (1.0f - BETA) * h1.z;
        o1.w = BETA * acc[i][7] + (1.0f - BETA) * h1.w;
        ((float4*)hr)[0] = o0;
        ((float4*)hr)[1] = o1;
    }
}

extern "C" void kernel_launch(void* const* d_in, const int* in_sizes, int n_in,
                              void* d_out, int out_size, void* d_ws, size_t ws_size,
                              hipStream_t stream) {
    const float* x      = (const float*)d_in[0];
    const int*   ei     = (const int*)d_in[1];
    const float* attr   = (const float*)d_in[2];
    const float* init_x = (const float*)d_in[3];
    const float* W      = (const float*)d_in[4];
    float* out = (float*)d_out;

    const int N = in_sizes[0] / C_DIM;
    const int E = in_sizes[2];

    const int N_pad = (N + 255) & ~255;
    const size_t xb_bytes  = (size_t)N * C_DIM * 2;       // bf16 copy of x
    const size_t cnt_bytes = (size_t)N_pad * 4;
    const size_t rec_bytes = (size_t)E * 8;
    const size_t need_full = xb_bytes + cnt_bytes + 1024 + rec_bytes;
    const bool use_bf16 = ws_size >= need_full;

    char* wsp = (char*)d_ws;
    uint4* xb = nullptr;
    if (use_bf16) { xb = (uint4*)wsp; wsp += xb_bytes; }
    int*    cnt      = (int*)wsp;
    int*    partials = cnt + N_pad;
    float2* recs     = (float2*)((char*)partials + 1024);

    const int B = (N + 1023) / 1024;   // scan blocks (98 for N=100000), must be <=256
    const int n8 = use_bf16 ? (N * C_DIM / 8) : 0;
    const int prep_elems = (n8 > N) ? n8 : N;

    k_prep<<<(prep_elems + 255) / 256, 256, 0, stream>>>((const float4*)x, xb, n8, cnt, N);
    k_hist<<<(E + 255) / 256, 256, 0, stream>>>(ei, cnt, E);
    k_blockreduce<<<B, 256, 0, stream>>>(cnt, partials, N);
    k_blockscan<<<B, 256, 0, stream>>>(cnt, partials, N);
    k_build<<<(E + 255) / 256, 256, 0, stream>>>(ei, attr, cnt, recs, E);
    if (use_bf16) {
        k_gather<1><<<(N + 7) / 8, 256, 0, stream>>>((const void*)xb, cnt, recs,
                                                     (const float4*)init_x, (float4*)out, N);
    } else {
        k_gather<0><<<(N + 7) / 8, 256, 0, stream>>>((const void*)x, cnt, recs,
                                                     (const float4*)init_x, (float4*)out, N);
    }
    k_gemm_blend<<<(N + 63) / 64, 256, 0, stream>>>(W, out, N);
}

// Round 5
// 155.095 us; speedup vs baseline: 7.4457x; 1.1795x over previous
//
#include <hip/hip_runtime.h>

// GCNII layer: N=100000 nodes, C=128, E=640000 edges, fp32.
//   hidden = (1-ALPHA) * segment_sum(attr * x[col], row) + ALPHA * init_x
//   out    = BETA * (hidden @ W) + (1-BETA) * hidden
//          = hidden @ (BETA*W + (1-BETA)*I)          <- blend folded into W
//
// Pipeline: prep (x->bf16 + zero cnt) + prepw (W -> folded/transposed bf16) ->
// hist -> blockreduce -> blockscan -> build packed CSR -> gather (4-way
// unrolled, writes fp32 hidden to d_out) -> MFMA GEMM in-place on d_out.
// Workspace: cnt[N_pad] | partials[256] | recs[E f2] | Wt[128*128 bf16] | xb[N*128 bf16].

#define ALPHA 0.1f
#define BETA  0.5f
#define C_DIM 128

typedef __attribute__((ext_vector_type(8))) short short8v;   // 8 bf16 (4 VGPR)
typedef __attribute__((ext_vector_type(4))) float f32x4;

__device__ inline unsigned bf16rn(float f) {            // RTNE fp32->bf16 bits
    unsigned u = __float_as_uint(f);
    return (u + 0x7FFFu + ((u >> 16) & 1u)) >> 16;
}
__device__ inline unsigned pack2(float lo, float hi) {
    return bf16rn(lo) | (bf16rn(hi) << 16);
}
__device__ inline short8v pack_a(float4 lo, float4 hi) {
    union { ushort u[8]; short8v v; } r;
    r.u[0] = (ushort)bf16rn(lo.x); r.u[1] = (ushort)bf16rn(lo.y);
    r.u[2] = (ushort)bf16rn(lo.z); r.u[3] = (ushort)bf16rn(lo.w);
    r.u[4] = (ushort)bf16rn(hi.x); r.u[5] = (ushort)bf16rn(hi.y);
    r.u[6] = (ushort)bf16rn(hi.z); r.u[7] = (ushort)bf16rn(hi.w);
    return r.v;
}

// K0: convert x -> bf16 (8 elems/thread) and zero cnt[N]. xb may be null.
__global__ void k_prep(const float4* __restrict__ x4, uint4* __restrict__ xb,
                       int n8, int* __restrict__ cnt, int N) {
    int i = blockIdx.x * 256 + threadIdx.x;
    if (i < n8) {
        float4 a = x4[2 * i], b = x4[2 * i + 1];
        uint4 o;
        o.x = pack2(a.x, a.y); o.y = pack2(a.z, a.w);
        o.z = pack2(b.x, b.y); o.w = pack2(b.z, b.w);
        xb[i] = o;
    }
    if (i < N) cnt[i] = 0;
}

// K0b: Wt[n][k] = bf16( BETA*W[k][n] + (k==n)*(1-BETA) )   (transposed + folded)
__global__ void k_prepw(const float* __restrict__ W, ushort* __restrict__ Wt) {
    int i = blockIdx.x * 256 + threadIdx.x;   // 16384 threads
    int n = i >> 7, k = i & 127;
    float v = BETA * W[k * C_DIM + n] + ((k == n) ? (1.0f - BETA) : 0.0f);
    Wt[i] = (ushort)bf16rn(v);
}

__global__ void k_hist(const int* __restrict__ ei, int* __restrict__ cnt, int E) {
    int e = blockIdx.x * 256 + threadIdx.x;
    if (e < E) atomicAdd(&cnt[ei[e]], 1);
}

// partials[b] = sum of cnt[b*1024 .. b*1024+1024)
__global__ void k_blockreduce(const int* __restrict__ cnt, int* __restrict__ partials, int n) {
    __shared__ int lds[256];
    int t = threadIdx.x;
    int base = blockIdx.x * 1024;
    int s = 0;
#pragma unroll
    for (int j = 0; j < 4; ++j) {
        int idx = base + j * 256 + t;
        if (idx < n) s += cnt[idx];
    }
    lds[t] = s;
    __syncthreads();
    for (int d = 128; d > 0; d >>= 1) {
        if (t < d) lds[t] += lds[t + d];
        __syncthreads();
    }
    if (t == 0) partials[blockIdx.x] = lds[0];
}

// block b: exclusive scan of cnt[b*1024 ..] in place; base = sum(partials[<b])
// (requires gridDim.x <= 256)
__global__ void k_blockscan(int* __restrict__ cnt, const int* __restrict__ partials, int n) {
    __shared__ int lds[256];
    __shared__ int base_s;
    int t = threadIdx.x;

    int pv = (t < blockIdx.x) ? partials[t] : 0;
    lds[t] = pv;
    __syncthreads();
    for (int d = 128; d > 0; d >>= 1) {
        if (t < d) lds[t] += lds[t + d];
        __syncthreads();
    }
    if (t == 0) base_s = lds[0];
    __syncthreads();

    int base = blockIdx.x * 1024 + t * 4;
    int4 v = {0, 0, 0, 0};
    if (base + 3 < n) v = *(const int4*)(cnt + base);
    else {
        if (base + 0 < n) v.x = cnt[base + 0];
        if (base + 1 < n) v.y = cnt[base + 1];
        if (base + 2 < n) v.z = cnt[base + 2];
        if (base + 3 < n) v.w = cnt[base + 3];
    }
    int s = v.x + v.y + v.z + v.w;
    lds[t] = s;
    for (int d = 1; d < 256; d <<= 1) {
        __syncthreads();
        int tmp = (t >= d) ? lds[t - d] : 0;
        __syncthreads();
        lds[t] += tmp;
    }
    __syncthreads();
    int thrBase = base_s + lds[t] - s;
    int4 o;
    o.x = thrBase;
    o.y = thrBase + v.x;
    o.z = thrBase + v.x + v.y;
    o.w = thrBase + v.x + v.y + v.z;
    if (base + 3 < n) *(int4*)(cnt + base) = o;
    else {
        if (base + 0 < n) cnt[base + 0] = o.x;
        if (base + 1 < n) cnt[base + 1] = o.y;
        if (base + 2 < n) cnt[base + 2] = o.z;
        if (base + 3 < n) cnt[base + 3] = o.w;
    }
}

// bin edges into CSR order as packed 8B records (col, attr*(1-ALPHA))
__global__ void k_build(const int* __restrict__ ei, const float* __restrict__ attr,
                        int* __restrict__ cur, float2* __restrict__ recs, int E) {
    int e = blockIdx.x * 256 + threadIdx.x;
    if (e >= E) return;
    int row = ei[e];
    int pos = atomicAdd(&cur[row], 1);
    recs[pos] = make_float2(__int_as_float(ei[E + e]), (1.0f - ALPHA) * attr[e]);
}

__device__ inline void bf16_fma4(float4& acc, float a, uint2 v) {
    acc.x += a * __uint_as_float(v.x << 16);
    acc.y += a * __uint_as_float(v.x & 0xffff0000u);
    acc.z += a * __uint_as_float(v.y << 16);
    acc.w += a * __uint_as_float(v.y & 0xffff0000u);
}

// per-row gather-reduce + ALPHA*init_x. 32 lanes/row, 4 channels/lane.
// 4-way edge unroll for memory-level parallelism (edges are latency-bound).
// post-build cnt[r] = end of row r; start = cnt[r-1].
template <int USE_BF16>
__global__ __launch_bounds__(256)
void k_gather(const void* __restrict__ xsrc, const int* __restrict__ cnt,
              const float2* __restrict__ recs,
              const float4* __restrict__ init4, float4* __restrict__ out4, int N) {
    int r = blockIdx.x * 8 + (threadIdx.x >> 5);
    if (r >= N) return;
    int c4 = threadIdx.x & 31;
    int start = (r == 0) ? 0 : cnt[r - 1];
    int end = cnt[r];
    float4 acc = {0.f, 0.f, 0.f, 0.f};
    int k = start;
    if (USE_BF16) {
        const uint2* xb2 = (const uint2*)xsrc;
        for (; k + 4 <= end; k += 4) {
            float2 r0 = recs[k + 0];
            float2 r1 = recs[k + 1];
            float2 r2 = recs[k + 2];
            float2 r3 = recs[k + 3];
            uint2 v0 = xb2[(size_t)__float_as_int(r0.x) * 32 + c4];
            uint2 v1 = xb2[(size_t)__float_as_int(r1.x) * 32 + c4];
            uint2 v2 = xb2[(size_t)__float_as_int(r2.x) * 32 + c4];
            uint2 v3 = xb2[(size_t)__float_as_int(r3.x) * 32 + c4];
            bf16_fma4(acc, r0.y, v0);
            bf16_fma4(acc, r1.y, v1);
            bf16_fma4(acc, r2.y, v2);
            bf16_fma4(acc, r3.y, v3);
        }
        if (k + 2 <= end) {
            float2 r0 = recs[k + 0];
            float2 r1 = recs[k + 1];
            uint2 v0 = xb2[(size_t)__float_as_int(r0.x) * 32 + c4];
            uint2 v1 = xb2[(size_t)__float_as_int(r1.x) * 32 + c4];
            bf16_fma4(acc, r0.y, v0);
            bf16_fma4(acc, r1.y, v1);
            k += 2;
        }
        if (k < end) {
            float2 r0 = recs[k];
            uint2 v0 = xb2[(size_t)__float_as_int(r0.x) * 32 + c4];
            bf16_fma4(acc, r0.y, v0);
        }
    } else {
        const float4* x4 = (const float4*)xsrc;
        for (; k < end; ++k) {
            float2 rec = recs[k];
            int col = __float_as_int(rec.x);
            float a = rec.y;
            float4 xv = x4[(size_t)col * 32 + c4];
            acc.x += a * xv.x; acc.y += a * xv.y;
            acc.z += a * xv.z; acc.w += a * xv.w;
        }
    }
    float4 iv = init4[(size_t)r * 32 + c4];
    float4 o;
    o.x = acc.x + ALPHA * iv.x;
    o.y = acc.y + ALPHA * iv.y;
    o.z = acc.z + ALPHA * iv.z;
    o.w = acc.w + ALPHA * iv.w;
    out4[(size_t)r * 32 + c4] = o;
}

// MFMA GEMM, in place on h (= d_out):  h = h_bf16 @ Wt'   (blend folded in Wt').
// 4 waves/block; wave owns 32 rows (2 M-tiles of 16), all 128 cols.
// A frags: fp32 rows -> bf16 in-register. B frags: 16B loads from 32KB Wt
// (L1-resident, no LDS -> no bank conflicts, no barriers).
// Race-free in place: a wave loads only the rows it stores; stores issue after
// the final MFMA has consumed all loads. Tail-block clamped loads feed only
// discarded (store-guarded) results.
__global__ __launch_bounds__(256)
void k_gemm_mfma(const ushort* __restrict__ Wt, float* __restrict__ h, int N) {
    const uint4* W16 = (const uint4*)Wt;        // Wt[n][k]: 16 uint4 per row
    int lane = threadIdx.x & 63;
    int wv   = threadIdx.x >> 6;
    int m = lane & 15, g = lane >> 4;
    long R0 = (long)blockIdx.x * 128 + wv * 32;

    f32x4 acc[2][8];
#pragma unroll
    for (int t = 0; t < 2; ++t)
#pragma unroll
        for (int nt = 0; nt < 8; ++nt) acc[t][nt] = (f32x4){0.f, 0.f, 0.f, 0.f};

#pragma unroll
    for (int ks = 0; ks < 4; ++ks) {
        int kb = ks * 32 + g * 8;               // A: lane holds A[m][kb..kb+7]
        short8v a[2];
#pragma unroll
        for (int t = 0; t < 2; ++t) {
            long r = R0 + t * 16 + m;
            if (r >= N) r = N - 1;              // clamped reads -> discarded results
            const float4* hp = (const float4*)(h + r * C_DIM + kb);
            a[t] = pack_a(hp[0], hp[1]);
        }
#pragma unroll
        for (int nt = 0; nt < 8; ++nt) {
            union { uint4 q; short8v v; } b;    // B: lane holds Wf[kb..kb+7][nt*16+m]
            b.q = W16[(nt * 16 + m) * 16 + (ks * 4 + g)];
            acc[0][nt] = __builtin_amdgcn_mfma_f32_16x16x32_bf16(a[0], b.v, acc[0][nt], 0, 0, 0);
            acc[1][nt] = __builtin_amdgcn_mfma_f32_16x16x32_bf16(a[1], b.v, acc[1][nt], 0, 0, 0);
        }
    }

    // C/D layout: col = lane&15, row = (lane>>4)*4 + reg
#pragma unroll
    for (int t = 0; t < 2; ++t) {
        long rb = R0 + t * 16 + g * 4;
#pragma unroll
        for (int reg = 0; reg < 4; ++reg) {
            long r = rb + reg;
            if (r >= N) continue;
            float* outp = h + r * C_DIM + m;
#pragma unroll
            for (int nt = 0; nt < 8; ++nt) outp[nt * 16] = acc[t][nt][reg];
        }
    }
}

extern "C" void kernel_launch(void* const* d_in, const int* in_sizes, int n_in,
                              void* d_out, int out_size, void* d_ws, size_t ws_size,
                              hipStream_t stream) {
    const float* x      = (const float*)d_in[0];
    const int*   ei     = (const int*)d_in[1];
    const float* attr   = (const float*)d_in[2];
    const float* init_x = (const float*)d_in[3];
    const float* W      = (const float*)d_in[4];
    float* out = (float*)d_out;

    const int N = in_sizes[0] / C_DIM;
    const int E = in_sizes[2];

    const int N_pad = (N + 255) & ~255;
    const size_t cnt_bytes = (size_t)N_pad * 4;
    const size_t rec_bytes = (size_t)E * 8;
    const size_t wt_bytes  = (size_t)C_DIM * C_DIM * 2;   // 32 KB
    const size_t xb_bytes  = (size_t)N * C_DIM * 2;       // bf16 copy of x
    const size_t base_need = cnt_bytes + 1024 + rec_bytes + wt_bytes;
    const bool use_bf16 = ws_size >= base_need + xb_bytes;

    char* wsp = (char*)d_ws;
    int*    cnt      = (int*)wsp;
    int*    partials = cnt + N_pad;
    float2* recs     = (float2*)((char*)partials + 1024);
    ushort* Wt       = (ushort*)((char*)recs + rec_bytes);
    uint4*  xb       = use_bf16 ? (uint4*)((char*)Wt + wt_bytes) : nullptr;

    const int B = (N + 1023) / 1024;   // scan blocks (98 for N=100000), must be <=256
    const int n8 = use_bf16 ? (N * C_DIM / 8) : 0;
    const int prep_elems = (n8 > N) ? n8 : N;

    k_prep<<<(prep_elems + 255) / 256, 256, 0, stream>>>((const float4*)x, xb, n8, cnt, N);
    k_prepw<<<C_DIM * C_DIM / 256, 256, 0, stream>>>(W, Wt);
    k_hist<<<(E + 255) / 256, 256, 0, stream>>>(ei, cnt, E);
    k_blockreduce<<<B, 256, 0, stream>>>(cnt, partials, N);
    k_blockscan<<<B, 256, 0, stream>>>(cnt, partials, N);
    k_build<<<(E + 255) / 256, 256, 0, stream>>>(ei, attr, cnt, recs, E);
    if (use_bf16) {
        k_gather<1><<<(N + 7) / 8, 256, 0, stream>>>((const void*)xb, cnt, recs,
                                                     (const float4*)init_x, (float4*)out, N);
    } else {
        k_gather<0><<<(N + 7) / 8, 256, 0, stream>>>((const void*)x, cnt, recs,
                                                     (const float4*)init_x, (float4*)out, N);
    }
    k_gemm_mfma<<<(N + 127) / 128, 256, 0, stream>>>(Wt, out, N);
}